// Round 5
// baseline (32077.786 us; speedup 1.0000x reference)
//
#include <hip/hip_runtime.h>
#include <cstdint>
#include <cstddef>

#define BB 2
#define NN 16384
#define SS 4096
#define KK 32
#define FIN 16
#define R2C 0.01f
#define NCHUNK 256   // chunks of exactly 64 points (counting-sorted by 8^3 cell)

// ---------------- DPP wave argmax (val desc, tie -> lowest idx) ----------------
// update_dpp(old=own, src=own): invalid lanes read their own value -> idempotent
// combine, safe for argmax regardless of bound_ctrl semantics.
template <int CTRL>
__device__ __forceinline__ void amax_step(float& v, int& i) {
  const int vi = __float_as_int(v);
  const int nvi = __builtin_amdgcn_update_dpp(vi, vi, CTRL, 0xf, 0xf, false);
  const int ni = __builtin_amdgcn_update_dpp(i, i, CTRL, 0xf, 0xf, false);
  const float nv = __int_as_float(nvi);
  const bool take = (nv > v) || (nv == v && ni < i);
  v = take ? nv : v;
  i = take ? ni : i;
}
// after this, lane 63 holds the full 64-lane argmax
__device__ __forceinline__ void amax_wave(float& v, int& i) {
  amax_step<0x111>(v, i);  // row_shr:1
  amax_step<0x112>(v, i);  // row_shr:2
  amax_step<0x114>(v, i);  // row_shr:4
  amax_step<0x118>(v, i);  // row_shr:8
  amax_step<0x142>(v, i);  // row_bcast15
  amax_step<0x143>(v, i);  // row_bcast31
}

// ---------------- binning: counting-sort points into 256 chunks ----------------
__global__ __launch_bounds__(512) void bin_kernel(const float* __restrict__ pos,
                                                  float4* __restrict__ cellpts,
                                                  float4* __restrict__ bboxLo,
                                                  float4* __restrict__ bboxHi) {
  const int b = blockIdx.x, t = threadIdx.x;
  const float* __restrict__ p = pos + (size_t)b * NN * 3;
  __shared__ int hist[512], sA[512], sB[512];
  hist[t] = 0;
  __syncthreads();
  int cidc[NN / 512];  // 32 per thread
#pragma unroll
  for (int m = 0; m < NN / 512; ++m) {
    const int i = m * 512 + t;
    const float x = p[i * 3 + 0], y = p[i * 3 + 1], z = p[i * 3 + 2];
    const int cx = min(7, (int)(x * 8.0f));
    const int cy = min(7, (int)(y * 8.0f));
    const int cz = min(7, (int)(z * 8.0f));
    const int cid = (cz * 8 + cy) * 8 + cx;
    cidc[m] = cid;
    atomicAdd(&hist[cid], 1);
  }
  __syncthreads();
  // Hillis-Steele inclusive scan over 512 entries (ping-pong)
  sA[t] = hist[t];
  __syncthreads();
  int* src = sA;
  int* dst = sB;
  for (int off = 1; off < 512; off <<= 1) {
    int v = src[t];
    if (t >= off) v += src[t - off];
    dst[t] = v;
    __syncthreads();
    int* tmp = src; src = dst; dst = tmp;
  }
  const int excl = (t == 0) ? 0 : src[t - 1];
  __syncthreads();
  hist[t] = excl;  // reuse as running offsets
  __syncthreads();
#pragma unroll
  for (int m = 0; m < NN / 512; ++m) {
    const int i = m * 512 + t;
    const int slot = atomicAdd(&hist[cidc[m]], 1);
    cellpts[(size_t)b * NN + slot] =
        make_float4(p[i * 3 + 0], p[i * 3 + 1], p[i * 3 + 2], __int_as_float(i));
  }
  __threadfence_block();
  __syncthreads();
  if (t < NCHUNK) {
    float4 lo = make_float4(1e30f, 1e30f, 1e30f, 0.0f);
    float4 hi = make_float4(-1e30f, -1e30f, -1e30f, 0.0f);
    for (int k = 0; k < 64; ++k) {
      const float4 q = cellpts[(size_t)b * NN + t * 64 + k];
      lo.x = fminf(lo.x, q.x); lo.y = fminf(lo.y, q.y); lo.z = fminf(lo.z, q.z);
      hi.x = fmaxf(hi.x, q.x); hi.y = fmaxf(hi.y, q.y); hi.z = fmaxf(hi.z, q.z);
    }
    bboxLo[b * NCHUNK + t] = lo;
    bboxHi[b * NCHUNK + t] = hi;
  }
}

// ---------------- FPS: one WAVE per batch, exact AABB-pruned ----------------
__global__ __launch_bounds__(64) void fps_kernel(const float* __restrict__ pos,
                                                 const float4* __restrict__ cellpts,
                                                 const float4* __restrict__ bboxLo,
                                                 const float4* __restrict__ bboxHi,
                                                 int* __restrict__ idx_out) {
  const int b = blockIdx.x;
  const int lane = threadIdx.x;  // 0..63, single wave: no barriers anywhere
  const float* __restrict__ p = pos + (size_t)b * NN * 3;
  const float4* __restrict__ cp = cellpts + (size_t)b * NN;

  __shared__ float sDmin[NN];        // 64 KB, indexed by sorted slot
  __shared__ float4 sLo[NCHUNK], sHi[NCHUNK];
  __shared__ float sMaxV[NCHUNK];
  __shared__ int sMaxI[NCHUNK];
  __shared__ int sWl[NCHUNK];

#pragma unroll
  for (int g = 0; g < NCHUNK / 64; ++g) {
    const int c = g * 64 + lane;
    sLo[c] = bboxLo[b * NCHUNK + c];
    sHi[c] = bboxHi[b * NCHUNK + c];
    sMaxV[c] = 1e30f;  // forces all chunks active on iteration 1
    sMaxI[c] = 0;
  }
  for (int s = lane; s < NN; s += 64) sDmin[s] = 1e10f;
  if (lane == 0) idx_out[b * SS + 0] = 0;
  float lx = p[0], ly = p[1], lz = p[2];

  const unsigned long long below = (1ull << lane) - 1ull;

  for (int it = 1; it < SS; ++it) {
    // --- Phase A: AABB skip tests, build active-chunk worklist ---
    int nact = 0;
#pragma unroll
    for (int g = 0; g < NCHUNK / 64; ++g) {
      const int c = g * 64 + lane;
      const float4 lo = sLo[c];
      const float4 hi = sHi[c];
      const float ax = fmaxf(fmaxf(lo.x - lx, lx - hi.x), 0.0f);
      const float ay = fmaxf(fmaxf(lo.y - ly, ly - hi.y), 0.0f);
      const float az = fmaxf(fmaxf(lo.z - lz, lz - hi.z), 0.0f);
      const float bl2 = ax * ax + ay * ay + az * az;
      // skip iff bl2 (with 1e-5 conservative slack) exceeds chunk max dmin:
      // then min(dmin_j, d_j) == dmin_j exactly for every member point.
      const bool act = !(bl2 * 0.99999f > sMaxV[c]);
      const unsigned long long m = __ballot(act);
      if (act) {
        const int r = nact + (int)__popcll(m & below);
        sWl[r] = c;
      }
      nact += (int)__popcll(m);
    }
    nact = __builtin_amdgcn_readfirstlane(nact);

    // --- Phase B: process active chunks (64 pts each, 1 wave-pass per chunk) ---
    int c_cur = __builtin_amdgcn_readfirstlane(sWl[0]);  // nact >= 1 always
    float4 P = cp[(size_t)(c_cur * 64 + lane)];
    for (int w = 0; w < nact; ++w) {
      int c_nxt = 0;
      float4 Pn;
      if (w + 1 < nact) {  // uniform condition: prefetch next chunk
        c_nxt = __builtin_amdgcn_readfirstlane(sWl[w + 1]);
        Pn = cp[(size_t)(c_nxt * 64 + lane)];
      }
      const int slot = c_cur * 64 + lane;
      const float od = sDmin[slot];
      // exact np order: (dx*dx + dy*dy) + dz*dz, no FMA contraction
      const float dx = P.x - lx, dy = P.y - ly, dz = P.z - lz;
      const float d = __fadd_rn(__fadd_rn(__fmul_rn(dx, dx), __fmul_rn(dy, dy)),
                                __fmul_rn(dz, dz));
      const float dm = fminf(od, d);
      sDmin[slot] = dm;
      float rv = dm;
      int ri = __float_as_int(P.w);  // original point index (bit-cast)
      amax_wave(rv, ri);
      if (lane == 63) { sMaxV[c_cur] = rv; sMaxI[c_cur] = ri; }
      c_cur = c_nxt;
      P = Pn;
    }

    // --- Phase C: global argmax over 256 chunk maxima ---
    float bv = -1.0f;
    int bi = 0;
#pragma unroll
    for (int g = 0; g < NCHUNK / 64; ++g) {
      const int c = g * 64 + lane;
      const float v = sMaxV[c];
      const int i = sMaxI[c];
      const bool take = (v > bv) || (v == bv && i < bi);
      bv = take ? v : bv;
      bi = take ? i : bi;
    }
    amax_wave(bv, bi);
    const int fi = __builtin_amdgcn_readlane(bi, 63);
    if (lane == 0) idx_out[b * SS + it] = fi;
    // uniform scalar loads of the winner's coords
    lx = p[fi * 3 + 0];
    ly = p[fi * 3 + 1];
    lz = p[fi * 3 + 2];
  }
}

// ---------------- Ball query: one wave per centroid ----------------
__global__ __launch_bounds__(256) void ballq_kernel(const float* __restrict__ pos,
                                                    const int* __restrict__ idx,
                                                    int* __restrict__ nbr,
                                                    int* __restrict__ cnt,
                                                    float* __restrict__ outC,
                                                    float* __restrict__ outB) {
  const int cs = blockIdx.x * 4 + (threadIdx.x >> 6);
  const int lane = threadIdx.x & 63;
  const int b = cs >> 12;           // S = 4096
  const int s = cs & (SS - 1);
  const float* __restrict__ p = pos + (size_t)b * NN * 3;
  const int ci = idx[cs];
  const float cx = p[ci * 3 + 0], cy = p[ci * 3 + 1], cz = p[ci * 3 + 2];
  // remove_self_loops: global src b*N+i == global dst b*S+s -> only b==0, i==s
  const int excl = (b == 0) ? s : -1;
  int count = 0;
  for (int tile = 0; tile < NN / 64; ++tile) {
    const int i = tile * 64 + lane;
    const float dx = cx - p[i * 3 + 0];
    const float dy = cy - p[i * 3 + 1];
    const float dz = cz - p[i * 3 + 2];
    const float d2 = __fadd_rn(__fadd_rn(__fmul_rn(dx, dx), __fmul_rn(dy, dy)), __fmul_rn(dz, dz));
    const bool in = (d2 <= R2C) && (i != excl);
    const unsigned long long m = __ballot(in);
    if (in) {
      const int rank = count + (int)__popcll(m & ((1ull << lane) - 1ull));
      if (rank < KK) nbr[cs * KK + rank] = i;
    }
    count += (int)__popcll(m);
    if (count >= KK) break;
  }
  if (lane == 0) {
    cnt[cs] = count < KK ? count : KK;
    outC[cs * 3 + 0] = cx;
    outC[cs * 3 + 1] = cy;
    outC[cs * 3 + 2] = cz;
    outB[cs] = (float)b;
  }
}

// ---------------- MLP + max: one block (128 thr) per centroid ----------------
#define EE 33
__global__ __launch_bounds__(128) void mlp_kernel(const float* __restrict__ x,
                                                  const float* __restrict__ pos,
                                                  const int* __restrict__ nbr,
                                                  const int* __restrict__ cnt,
                                                  const float* __restrict__ W1,
                                                  const float* __restrict__ b1,
                                                  const float* __restrict__ W2,
                                                  const float* __restrict__ b2,
                                                  const float* __restrict__ W3,
                                                  const float* __restrict__ b3,
                                                  const float* __restrict__ outC,
                                                  float* __restrict__ outX) {
  __shared__ float sF[EE][20];
  __shared__ float sH1[EE][64];
  __shared__ float sH2[EE][64];
  __shared__ int sValid[EE];

  const int cs = blockIdx.x;
  const int tid = threadIdx.x;
  const int b = cs >> 12;
  const int c = tid & 63;
  const int half = tid >> 6;

  float w1c[19], w2c[64], w3c[64];
#pragma unroll
  for (int k = 0; k < 19; ++k) w1c[k] = W1[k * 64 + c];
#pragma unroll
  for (int k = 0; k < 64; ++k) w2c[k] = W2[k * 64 + c];
#pragma unroll
  for (int k = 0; k < 64; ++k) w3c[k] = W3[k * 128 + tid];
  const float b1c = b1[c], b2c = b2[c], b3c = b3[tid];

  if (tid < EE) {
    const float ccx = outC[cs * 3 + 0], ccy = outC[cs * 3 + 1], ccz = outC[cs * 3 + 2];
    int row;
    bool valid;
    if (tid < KK) {
      const int cn = cnt[cs];
      valid = tid < cn;
      const int j = valid ? nbr[cs * KK + tid] : 0;
      row = b * NN + j;
    } else {
      // PyG add_self_loops quirk: src is flat point index dflat = b*S+s = cs
      valid = true;
      row = cs;
    }
    for (int f = 0; f < FIN; ++f) sF[tid][f] = x[(size_t)row * FIN + f];
    sF[tid][16] = pos[(size_t)row * 3 + 0] - ccx;
    sF[tid][17] = pos[(size_t)row * 3 + 1] - ccy;
    sF[tid][18] = pos[(size_t)row * 3 + 2] - ccz;
    sValid[tid] = valid ? 1 : 0;
  }
  __syncthreads();
  for (int e = half; e < EE; e += 2) {
    float acc = b1c;
#pragma unroll
    for (int k = 0; k < 19; ++k) acc += sF[e][k] * w1c[k];
    sH1[e][c] = fmaxf(acc, 0.0f);
  }
  __syncthreads();
  for (int e = half; e < EE; e += 2) {
    float acc = b2c;
#pragma unroll
    for (int k = 0; k < 64; ++k) acc += sH1[e][k] * w2c[k];
    sH2[e][c] = fmaxf(acc, 0.0f);
  }
  __syncthreads();
  float mx = -1e30f;
  for (int e = 0; e < EE; ++e) {
    if (sValid[e]) {
      float acc = b3c;
#pragma unroll
      for (int k = 0; k < 64; ++k) acc += sH2[e][k] * w3c[k];
      mx = fmaxf(mx, acc);
    }
  }
  outX[(size_t)cs * 128 + tid] = mx;
}

extern "C" void kernel_launch(void* const* d_in, const int* in_sizes, int n_in,
                              void* d_out, int out_size, void* d_ws, size_t ws_size,
                              hipStream_t stream) {
  const float* x = (const float*)d_in[0];
  const float* pos = (const float*)d_in[1];
  const float* W1 = (const float*)d_in[3];
  const float* b1 = (const float*)d_in[4];
  const float* W2 = (const float*)d_in[5];
  const float* b2 = (const float*)d_in[6];
  const float* W3 = (const float*)d_in[7];
  const float* b3 = (const float*)d_in[8];

  float* out = (float*)d_out;
  float* outX = out;                               // [B*S,128]
  float* outC = out + (size_t)BB * SS * 128;       // [B*S,3]
  float* outB = outC + (size_t)BB * SS * 3;        // [B*S]

  // workspace layout (16B-aligned pieces first)
  float4* cellpts = (float4*)d_ws;                         // BB*NN float4
  float4* bboxLo = cellpts + (size_t)BB * NN;              // BB*256
  float4* bboxHi = bboxLo + BB * NCHUNK;                   // BB*256
  int* idx = (int*)(bboxHi + BB * NCHUNK);                 // BB*SS
  int* nbr = idx + BB * SS;                                // BB*SS*KK
  int* cnt = nbr + (size_t)BB * SS * KK;                   // BB*SS

  hipLaunchKernelGGL(bin_kernel, dim3(BB), dim3(512), 0, stream, pos, cellpts, bboxLo, bboxHi);
  hipLaunchKernelGGL(fps_kernel, dim3(BB), dim3(64), 0, stream, pos, cellpts, bboxLo, bboxHi, idx);
  hipLaunchKernelGGL(ballq_kernel, dim3(BB * SS / 4), dim3(256), 0, stream,
                     pos, idx, nbr, cnt, outC, outB);
  hipLaunchKernelGGL(mlp_kernel, dim3(BB * SS), dim3(128), 0, stream,
                     x, pos, nbr, cnt, W1, b1, W2, b2, W3, b3, outC, outX);
}

// Round 6
// 9173.676 us; speedup vs baseline: 3.4967x; 3.4967x over previous
//
#include <hip/hip_runtime.h>
#include <cstdint>
#include <cstddef>

#define BB 2
#define NN 16384
#define SS 4096
#define KK 32
#define FIN 16
#define R2C 0.01f
#define NCHUNK 256   // chunks = 64-slot ranges of the cell-sorted point array

// ---------------- DPP wave argmax (val desc, tie -> lowest idx) ----------------
template <int CTRL>
__device__ __forceinline__ void amax_step(float& v, int& i) {
  const int vi = __float_as_int(v);
  const int nvi = __builtin_amdgcn_update_dpp(vi, vi, CTRL, 0xf, 0xf, false);
  const int ni = __builtin_amdgcn_update_dpp(i, i, CTRL, 0xf, 0xf, false);
  const float nv = __int_as_float(nvi);
  const bool take = (nv > v) || (nv == v && ni < i);
  v = take ? nv : v;
  i = take ? ni : i;
}
// after this, lane 63 holds the full 64-lane argmax
__device__ __forceinline__ void amax_wave(float& v, int& i) {
  amax_step<0x111>(v, i);  // row_shr:1
  amax_step<0x112>(v, i);  // row_shr:2
  amax_step<0x114>(v, i);  // row_shr:4
  amax_step<0x118>(v, i);  // row_shr:8
  amax_step<0x142>(v, i);  // row_bcast15
  amax_step<0x143>(v, i);  // row_bcast31
}

// ---------------- binning: counting-sort points into 256 chunks ----------------
__global__ __launch_bounds__(512) void bin_kernel(const float* __restrict__ pos,
                                                  float4* __restrict__ cellpts,
                                                  float4* __restrict__ bboxLo,
                                                  float4* __restrict__ bboxHi) {
  const int b = blockIdx.x, t = threadIdx.x;
  const float* __restrict__ p = pos + (size_t)b * NN * 3;
  __shared__ int hist[512], sA[512], sB[512];
  hist[t] = 0;
  __syncthreads();
  int cidc[NN / 512];  // 32 per thread
#pragma unroll
  for (int m = 0; m < NN / 512; ++m) {
    const int i = m * 512 + t;
    const float x = p[i * 3 + 0], y = p[i * 3 + 1], z = p[i * 3 + 2];
    const int cx = min(7, (int)(x * 8.0f));
    const int cy = min(7, (int)(y * 8.0f));
    const int cz = min(7, (int)(z * 8.0f));
    const int cid = (cz * 8 + cy) * 8 + cx;
    cidc[m] = cid;
    atomicAdd(&hist[cid], 1);
  }
  __syncthreads();
  sA[t] = hist[t];
  __syncthreads();
  int* src = sA;
  int* dst = sB;
  for (int off = 1; off < 512; off <<= 1) {
    int v = src[t];
    if (t >= off) v += src[t - off];
    dst[t] = v;
    __syncthreads();
    int* tmp = src; src = dst; dst = tmp;
  }
  const int excl = (t == 0) ? 0 : src[t - 1];
  __syncthreads();
  hist[t] = excl;
  __syncthreads();
#pragma unroll
  for (int m = 0; m < NN / 512; ++m) {
    const int i = m * 512 + t;
    const int slot = atomicAdd(&hist[cidc[m]], 1);
    cellpts[(size_t)b * NN + slot] =
        make_float4(p[i * 3 + 0], p[i * 3 + 1], p[i * 3 + 2], __int_as_float(i));
  }
  __threadfence_block();
  __syncthreads();
  if (t < NCHUNK) {
    float4 lo = make_float4(1e30f, 1e30f, 1e30f, 0.0f);
    float4 hi = make_float4(-1e30f, -1e30f, -1e30f, 0.0f);
    for (int k = 0; k < 64; ++k) {
      const float4 q = cellpts[(size_t)b * NN + t * 64 + k];
      lo.x = fminf(lo.x, q.x); lo.y = fminf(lo.y, q.y); lo.z = fminf(lo.z, q.z);
      hi.x = fmaxf(hi.x, q.x); hi.y = fmaxf(hi.y, q.y); hi.z = fmaxf(hi.z, q.z);
    }
    bboxLo[b * NCHUNK + t] = lo;
    bboxHi[b * NCHUNK + t] = hi;
  }
}

// ---------------- FPS: one 512-thread block (8 waves) per batch ----------------
// Exact AABB-pruned (bit-identical results, proven round 5); round 5's failure
// was single-wave latency serialization (~1400 cyc/chunk, unhidden). Here the
// active-chunk worklist is processed round-robin by 8 waves with 2-deep global
// prefetch; two barriers per iteration.
__global__ __launch_bounds__(512, 1) void fps_kernel(const float* __restrict__ pos,
                                                     const float4* __restrict__ cellpts,
                                                     const float4* __restrict__ bboxLo,
                                                     const float4* __restrict__ bboxHi,
                                                     int* __restrict__ idx_out) {
  const int b = blockIdx.x;
  const int t = threadIdx.x;
  const int wid = t >> 6;
  const int lane = t & 63;
  const float* __restrict__ p = pos + (size_t)b * NN * 3;
  const float4* __restrict__ cp = cellpts + (size_t)b * NN;

  __shared__ float sDmin[NN];                 // 64 KB, indexed by sorted slot
  __shared__ float4 sLo[NCHUNK], sHi[NCHUNK]; // 8 KB
  __shared__ float sMaxV[NCHUNK];             // exact per-chunk max dmin
  __shared__ int sMaxI[NCHUNK];
  __shared__ int sSeg[4][64];                 // per-wave compacted worklists
  __shared__ int sCnt[4];

  if (t < NCHUNK) {
    sLo[t] = bboxLo[b * NCHUNK + t];
    sHi[t] = bboxHi[b * NCHUNK + t];
    sMaxV[t] = 1e30f;  // all chunks active on iteration 1
    sMaxI[t] = 0;
  }
  for (int s = t; s < NN; s += 512) sDmin[s] = 1e10f;
  if (t == 0) idx_out[b * SS + 0] = 0;
  float lx = p[0], ly = p[1], lz = p[2];
  __syncthreads();

  const unsigned long long below = (1ull << lane) - 1ull;

  for (int it = 1; it < SS; ++it) {
    // --- Phase A: AABB tests (waves 0-3, one chunk per lane) ---
    if (wid < 4) {
      const int c = wid * 64 + lane;
      const float4 lo = sLo[c];
      const float4 hi = sHi[c];
      const float ax = fmaxf(fmaxf(lo.x - lx, lx - hi.x), 0.0f);
      const float ay = fmaxf(fmaxf(lo.y - ly, ly - hi.y), 0.0f);
      const float az = fmaxf(fmaxf(lo.z - lz, lz - hi.z), 0.0f);
      const float bl2 = ax * ax + ay * ay + az * az;
      // skip iff conservative lower bound exceeds chunk max dmin: then
      // min(dmin_j, d_j) == dmin_j exactly for every member (bit-exact skip).
      const bool act = !(bl2 * 0.99999f > sMaxV[c]);
      const unsigned long long m = __ballot(act);
      if (act) sSeg[wid][(int)__popcll(m & below)] = c;
      if (lane == 0) sCnt[wid] = (int)__popcll(m);
    }
    __syncthreads();

    const int c0 = sCnt[0], c1 = sCnt[1], c2 = sCnt[2], c3 = sCnt[3];
    const int nact = c0 + c1 + c2 + c3;
    const int e1 = c0 + c1, e2 = c0 + c1 + c2;

    // --- Phase B: active chunks round-robin over 8 waves, 2-deep prefetch ---
    int r = wid;
    int c_cur = -1;
    float4 P;
    if (r < nact) {
      c_cur = (r < c0) ? sSeg[0][r]
            : (r < e1) ? sSeg[1][r - c0]
            : (r < e2) ? sSeg[2][r - e1]
                       : sSeg[3][r - e2];
      P = cp[(size_t)((c_cur << 6) + lane)];
    }
    while (c_cur >= 0) {
      const int r2 = r + 8;
      int c_nxt = -1;
      float4 Pn;
      if (r2 < nact) {
        c_nxt = (r2 < c0) ? sSeg[0][r2]
              : (r2 < e1) ? sSeg[1][r2 - c0]
              : (r2 < e2) ? sSeg[2][r2 - e1]
                          : sSeg[3][r2 - e2];
        Pn = cp[(size_t)((c_nxt << 6) + lane)];
      }
      const int slot = (c_cur << 6) + lane;
      const float od = sDmin[slot];
      // exact np order: (dx*dx + dy*dy) + dz*dz, no FMA contraction
      const float dx = P.x - lx, dy = P.y - ly, dz = P.z - lz;
      const float d = __fadd_rn(__fadd_rn(__fmul_rn(dx, dx), __fmul_rn(dy, dy)),
                                __fmul_rn(dz, dz));
      const float dm = fminf(od, d);
      sDmin[slot] = dm;
      float rv = dm;
      int ri = __float_as_int(P.w);  // original point index
      amax_wave(rv, ri);
      if (lane == 63) { sMaxV[c_cur] = rv; sMaxI[c_cur] = ri; }
      r = r2;
      c_cur = c_nxt;
      P = Pn;
    }
    __syncthreads();

    // --- Phase C: all waves redundantly reduce 256 chunk maxima ---
    float bv = -1.0f;
    int bi = 0;
#pragma unroll
    for (int g = 0; g < NCHUNK / 64; ++g) {
      const int c = g * 64 + lane;
      const float v = sMaxV[c];
      const int i = sMaxI[c];
      const bool take = (v > bv) || (v == bv && i < bi);
      bv = take ? v : bv;
      bi = take ? i : bi;
    }
    amax_wave(bv, bi);
    const int fi = __builtin_amdgcn_readlane(bi, 63);
    if (t == 0) idx_out[b * SS + it] = fi;
    // uniform (scalar) loads of winner coords
    lx = p[fi * 3 + 0];
    ly = p[fi * 3 + 1];
    lz = p[fi * 3 + 2];
  }
}

// ---------------- Ball query: one wave per centroid ----------------
__global__ __launch_bounds__(256) void ballq_kernel(const float* __restrict__ pos,
                                                    const int* __restrict__ idx,
                                                    int* __restrict__ nbr,
                                                    int* __restrict__ cnt,
                                                    float* __restrict__ outC,
                                                    float* __restrict__ outB) {
  const int cs = blockIdx.x * 4 + (threadIdx.x >> 6);
  const int lane = threadIdx.x & 63;
  const int b = cs >> 12;           // S = 4096
  const int s = cs & (SS - 1);
  const float* __restrict__ p = pos + (size_t)b * NN * 3;
  const int ci = idx[cs];
  const float cx = p[ci * 3 + 0], cy = p[ci * 3 + 1], cz = p[ci * 3 + 2];
  // remove_self_loops: global src b*N+i == global dst b*S+s -> only b==0, i==s
  const int excl = (b == 0) ? s : -1;
  int count = 0;
  for (int tile = 0; tile < NN / 64; ++tile) {
    const int i = tile * 64 + lane;
    const float dx = cx - p[i * 3 + 0];
    const float dy = cy - p[i * 3 + 1];
    const float dz = cz - p[i * 3 + 2];
    const float d2 = __fadd_rn(__fadd_rn(__fmul_rn(dx, dx), __fmul_rn(dy, dy)), __fmul_rn(dz, dz));
    const bool in = (d2 <= R2C) && (i != excl);
    const unsigned long long m = __ballot(in);
    if (in) {
      const int rank = count + (int)__popcll(m & ((1ull << lane) - 1ull));
      if (rank < KK) nbr[cs * KK + rank] = i;
    }
    count += (int)__popcll(m);
    if (count >= KK) break;
  }
  if (lane == 0) {
    cnt[cs] = count < KK ? count : KK;
    outC[cs * 3 + 0] = cx;
    outC[cs * 3 + 1] = cy;
    outC[cs * 3 + 2] = cz;
    outB[cs] = (float)b;
  }
}

// ---------------- MLP + max: one block (128 thr) per centroid ----------------
#define EE 33
__global__ __launch_bounds__(128) void mlp_kernel(const float* __restrict__ x,
                                                  const float* __restrict__ pos,
                                                  const int* __restrict__ nbr,
                                                  const int* __restrict__ cnt,
                                                  const float* __restrict__ W1,
                                                  const float* __restrict__ b1,
                                                  const float* __restrict__ W2,
                                                  const float* __restrict__ b2,
                                                  const float* __restrict__ W3,
                                                  const float* __restrict__ b3,
                                                  const float* __restrict__ outC,
                                                  float* __restrict__ outX) {
  __shared__ float sF[EE][20];
  __shared__ float sH1[EE][64];
  __shared__ float sH2[EE][64];
  __shared__ int sValid[EE];

  const int cs = blockIdx.x;
  const int tid = threadIdx.x;
  const int b = cs >> 12;
  const int c = tid & 63;
  const int half = tid >> 6;

  float w1c[19], w2c[64], w3c[64];
#pragma unroll
  for (int k = 0; k < 19; ++k) w1c[k] = W1[k * 64 + c];
#pragma unroll
  for (int k = 0; k < 64; ++k) w2c[k] = W2[k * 64 + c];
#pragma unroll
  for (int k = 0; k < 64; ++k) w3c[k] = W3[k * 128 + tid];
  const float b1c = b1[c], b2c = b2[c], b3c = b3[tid];

  if (tid < EE) {
    const float ccx = outC[cs * 3 + 0], ccy = outC[cs * 3 + 1], ccz = outC[cs * 3 + 2];
    int row;
    bool valid;
    if (tid < KK) {
      const int cn = cnt[cs];
      valid = tid < cn;
      const int j = valid ? nbr[cs * KK + tid] : 0;
      row = b * NN + j;
    } else {
      // PyG add_self_loops quirk: src is flat point index dflat = b*S+s = cs
      valid = true;
      row = cs;
    }
    for (int f = 0; f < FIN; ++f) sF[tid][f] = x[(size_t)row * FIN + f];
    sF[tid][16] = pos[(size_t)row * 3 + 0] - ccx;
    sF[tid][17] = pos[(size_t)row * 3 + 1] - ccy;
    sF[tid][18] = pos[(size_t)row * 3 + 2] - ccz;
    sValid[tid] = valid ? 1 : 0;
  }
  __syncthreads();
  for (int e = half; e < EE; e += 2) {
    float acc = b1c;
#pragma unroll
    for (int k = 0; k < 19; ++k) acc += sF[e][k] * w1c[k];
    sH1[e][c] = fmaxf(acc, 0.0f);
  }
  __syncthreads();
  for (int e = half; e < EE; e += 2) {
    float acc = b2c;
#pragma unroll
    for (int k = 0; k < 64; ++k) acc += sH1[e][k] * w2c[k];
    sH2[e][c] = fmaxf(acc, 0.0f);
  }
  __syncthreads();
  float mx = -1e30f;
  for (int e = 0; e < EE; ++e) {
    if (sValid[e]) {
      float acc = b3c;
#pragma unroll
      for (int k = 0; k < 64; ++k) acc += sH2[e][k] * w3c[k];
      mx = fmaxf(mx, acc);
    }
  }
  outX[(size_t)cs * 128 + tid] = mx;
}

extern "C" void kernel_launch(void* const* d_in, const int* in_sizes, int n_in,
                              void* d_out, int out_size, void* d_ws, size_t ws_size,
                              hipStream_t stream) {
  const float* x = (const float*)d_in[0];
  const float* pos = (const float*)d_in[1];
  const float* W1 = (const float*)d_in[3];
  const float* b1 = (const float*)d_in[4];
  const float* W2 = (const float*)d_in[5];
  const float* b2 = (const float*)d_in[6];
  const float* W3 = (const float*)d_in[7];
  const float* b3 = (const float*)d_in[8];

  float* out = (float*)d_out;
  float* outX = out;                               // [B*S,128]
  float* outC = out + (size_t)BB * SS * 128;       // [B*S,3]
  float* outB = outC + (size_t)BB * SS * 3;        // [B*S]

  float4* cellpts = (float4*)d_ws;                         // BB*NN float4
  float4* bboxLo = cellpts + (size_t)BB * NN;              // BB*256
  float4* bboxHi = bboxLo + BB * NCHUNK;                   // BB*256
  int* idx = (int*)(bboxHi + BB * NCHUNK);                 // BB*SS
  int* nbr = idx + BB * SS;                                // BB*SS*KK
  int* cnt = nbr + (size_t)BB * SS * KK;                   // BB*SS

  hipLaunchKernelGGL(bin_kernel, dim3(BB), dim3(512), 0, stream, pos, cellpts, bboxLo, bboxHi);
  hipLaunchKernelGGL(fps_kernel, dim3(BB), dim3(512), 0, stream, pos, cellpts, bboxLo, bboxHi, idx);
  hipLaunchKernelGGL(ballq_kernel, dim3(BB * SS / 4), dim3(256), 0, stream,
                     pos, idx, nbr, cnt, outC, outB);
  hipLaunchKernelGGL(mlp_kernel, dim3(BB * SS), dim3(128), 0, stream,
                     x, pos, nbr, cnt, W1, b1, W2, b2, W3, b3, outC, outX);
}

// Round 7
// 6414.008 us; speedup vs baseline: 5.0012x; 1.4303x over previous
//
#include <hip/hip_runtime.h>
#include <cstdint>
#include <cstddef>

#define BB 2
#define NN 16384
#define SS 4096
#define KK 32
#define FIN 16
#define R2C 0.01f
#define NCHUNK 256   // chunks = 64-slot ranges of the Morton-cell-sorted point array

// ---------------- value-only DPP wave max (result valid at lane 63) ----------------
template <int CTRL>
__device__ __forceinline__ float vmax_step(float v) {
  const int nv = __builtin_amdgcn_update_dpp(__float_as_int(v), __float_as_int(v),
                                             CTRL, 0xf, 0xf, false);
  return fmaxf(v, __int_as_float(nv));
}
__device__ __forceinline__ float vmax_wave(float v) {
  v = vmax_step<0x111>(v);  // row_shr:1
  v = vmax_step<0x112>(v);  // row_shr:2
  v = vmax_step<0x114>(v);  // row_shr:4
  v = vmax_step<0x118>(v);  // row_shr:8
  v = vmax_step<0x142>(v);  // row_bcast15
  v = vmax_step<0x143>(v);  // row_bcast31
  return v;
}

// exact argmax index among lanes whose value == V (uniform); idxbits = original
// index bit-cast in a float reg. Tie -> lowest original index (matches np.argmax).
__device__ __forceinline__ int win_index(float dm, float V, float idxAsFloat) {
  const unsigned long long m = __ballot(dm == V);
  const int i0 = __builtin_amdgcn_readlane(__float_as_int(idxAsFloat),
                                           __ffsll((unsigned long long)m) - 1);
  if (__popcll(m) == 1) return i0;
  int best = i0;
  unsigned long long mm = m & (m - 1);
  while (mm) {
    const int l = __ffsll(mm) - 1;
    const int ii = __builtin_amdgcn_readlane(__float_as_int(idxAsFloat), l);
    best = ii < best ? ii : best;
    mm &= mm - 1;
  }
  return best;
}

// ---------------- binning: counting-sort points into Morton-ordered cells ----------------
__device__ __forceinline__ int part3(int x) {  // 3 bits -> bits 0,3,6
  return (x & 1) | ((x & 2) << 2) | ((x & 4) << 4);
}

__global__ __launch_bounds__(512) void bin_kernel(const float* __restrict__ pos,
                                                  float4* __restrict__ cellpts,
                                                  float4* __restrict__ bboxLo,
                                                  float4* __restrict__ bboxHi) {
  const int b = blockIdx.x, t = threadIdx.x;
  const float* __restrict__ p = pos + (size_t)b * NN * 3;
  __shared__ int hist[512], sA[512], sB[512];
  hist[t] = 0;
  __syncthreads();
  int cidc[NN / 512];  // 32 per thread
#pragma unroll
  for (int m = 0; m < NN / 512; ++m) {
    const int i = m * 512 + t;
    const float x = p[i * 3 + 0], y = p[i * 3 + 1], z = p[i * 3 + 2];
    const int cx = min(7, (int)(x * 8.0f));
    const int cy = min(7, (int)(y * 8.0f));
    const int cz = min(7, (int)(z * 8.0f));
    const int cid = part3(cx) | (part3(cy) << 1) | (part3(cz) << 2);  // Morton
    cidc[m] = cid;
    atomicAdd(&hist[cid], 1);
  }
  __syncthreads();
  sA[t] = hist[t];
  __syncthreads();
  int* src = sA;
  int* dst = sB;
  for (int off = 1; off < 512; off <<= 1) {
    int v = src[t];
    if (t >= off) v += src[t - off];
    dst[t] = v;
    __syncthreads();
    int* tmp = src; src = dst; dst = tmp;
  }
  const int excl = (t == 0) ? 0 : src[t - 1];
  __syncthreads();
  hist[t] = excl;
  __syncthreads();
#pragma unroll
  for (int m = 0; m < NN / 512; ++m) {
    const int i = m * 512 + t;
    const int slot = atomicAdd(&hist[cidc[m]], 1);
    cellpts[(size_t)b * NN + slot] =
        make_float4(p[i * 3 + 0], p[i * 3 + 1], p[i * 3 + 2], __int_as_float(i));
  }
  __threadfence_block();
  __syncthreads();
  if (t < NCHUNK) {
    float4 lo = make_float4(1e30f, 1e30f, 1e30f, 0.0f);
    float4 hi = make_float4(-1e30f, -1e30f, -1e30f, 0.0f);
    for (int k = 0; k < 64; ++k) {
      const float4 q = cellpts[(size_t)b * NN + t * 64 + k];
      lo.x = fminf(lo.x, q.x); lo.y = fminf(lo.y, q.y); lo.z = fminf(lo.z, q.z);
      hi.x = fmaxf(hi.x, q.x); hi.y = fmaxf(hi.y, q.y); hi.z = fmaxf(hi.z, q.z);
    }
    bboxLo[b * NCHUNK + t] = lo;
    bboxHi[b * NCHUNK + t] = hi;
  }
}

// ---------------- FPS: one 512-thread block (8 waves) per batch ----------------
// Exact AABB-pruned FPS (bit-identical, proven r5/r6). r7: Morton chunks (tight
// boxes), value-only DPP + ballot reduction, 1-chunk-ahead prefetch of both the
// global float4 and the LDS dmin read.
__global__ __launch_bounds__(512, 1) void fps_kernel(const float* __restrict__ pos,
                                                     const float4* __restrict__ cellpts,
                                                     const float4* __restrict__ bboxLo,
                                                     const float4* __restrict__ bboxHi,
                                                     int* __restrict__ idx_out) {
  const int b = blockIdx.x;
  const int t = threadIdx.x;
  const int wid = t >> 6;
  const int lane = t & 63;
  const float* __restrict__ p = pos + (size_t)b * NN * 3;
  const float4* __restrict__ cp = cellpts + (size_t)b * NN;

  __shared__ float sDmin[NN];                 // 64 KB, indexed by sorted slot
  __shared__ float4 sLo[NCHUNK], sHi[NCHUNK];
  __shared__ float sMaxV[NCHUNK];             // exact per-chunk max dmin
  __shared__ int sMaxI[NCHUNK];               // its argmax original index
  __shared__ int sSeg[4][64];                 // per-wave compacted worklists
  __shared__ int sCnt[4];

  if (t < NCHUNK) {
    sLo[t] = bboxLo[b * NCHUNK + t];
    sHi[t] = bboxHi[b * NCHUNK + t];
    sMaxV[t] = 1e30f;  // all chunks active on iteration 1
    sMaxI[t] = 0;
  }
  for (int s = t; s < NN; s += 512) sDmin[s] = 1e10f;
  if (t == 0) idx_out[b * SS + 0] = 0;
  float lx = p[0], ly = p[1], lz = p[2];
  __syncthreads();

  const unsigned long long below = (1ull << lane) - 1ull;

  for (int it = 1; it < SS; ++it) {
    // --- Phase A: AABB tests (waves 0-3, one chunk per lane) ---
    if (wid < 4) {
      const int c = wid * 64 + lane;
      const float4 lo = sLo[c];
      const float4 hi = sHi[c];
      const float ax = fmaxf(fmaxf(lo.x - lx, lx - hi.x), 0.0f);
      const float ay = fmaxf(fmaxf(lo.y - ly, ly - hi.y), 0.0f);
      const float az = fmaxf(fmaxf(lo.z - lz, lz - hi.z), 0.0f);
      const float bl2 = ax * ax + ay * ay + az * az;
      // skip iff conservative lower bound exceeds chunk max dmin: then
      // min(dmin_j, d_j) == dmin_j exactly for every member (bit-exact skip).
      const bool act = !(bl2 * 0.99999f > sMaxV[c]);
      const unsigned long long m = __ballot(act);
      if (act) sSeg[wid][(int)__popcll(m & below)] = c;
      if (lane == 0) sCnt[wid] = (int)__popcll(m);
    }
    __syncthreads();

    const int c0 = sCnt[0], c1 = sCnt[1], c2 = sCnt[2], c3 = sCnt[3];
    const int nact = c0 + c1 + c2 + c3;
    const int e1 = c0 + c1, e2 = c0 + c1 + c2;

    // --- Phase B: active chunks round-robin over 8 waves, prefetch cp+dmin ---
    int r = wid;
    int cA = -1;
    float4 PA;
    float odA = 0.0f;
    if (r < nact) {
      const int cid = (r < c0) ? sSeg[0][r]
                    : (r < e1) ? sSeg[1][r - c0]
                    : (r < e2) ? sSeg[2][r - e1]
                               : sSeg[3][r - e2];
      cA = __builtin_amdgcn_readfirstlane(cid);
      PA = cp[(size_t)((cA << 6) + lane)];
      odA = sDmin[(cA << 6) + lane];
    }
    while (cA >= 0) {
      const int r2 = r + 8;
      int cB = -1;
      float4 PB;
      float odB = 0.0f;
      if (r2 < nact) {
        const int cid = (r2 < c0) ? sSeg[0][r2]
                      : (r2 < e1) ? sSeg[1][r2 - c0]
                      : (r2 < e2) ? sSeg[2][r2 - e1]
                                  : sSeg[3][r2 - e2];
        cB = __builtin_amdgcn_readfirstlane(cid);
        PB = cp[(size_t)((cB << 6) + lane)];
        odB = sDmin[(cB << 6) + lane];
      }
      // exact np order: (dx*dx + dy*dy) + dz*dz, no FMA contraction
      const float dx = PA.x - lx, dy = PA.y - ly, dz = PA.z - lz;
      const float d = __fadd_rn(__fadd_rn(__fmul_rn(dx, dx), __fmul_rn(dy, dy)),
                                __fmul_rn(dz, dz));
      const float dm = fminf(odA, d);
      sDmin[(cA << 6) + lane] = dm;
      const float V = __int_as_float(
          __builtin_amdgcn_readlane(__float_as_int(vmax_wave(dm)), 63));
      const int bi = win_index(dm, V, PA.w);
      if (lane == 0) { sMaxV[cA] = V; sMaxI[cA] = bi; }
      r = r2;
      cA = cB;
      PA = PB;
      odA = odB;
    }
    __syncthreads();

    // --- Phase C: all waves redundantly reduce 256 chunk maxima ---
    float bv = -1.0f;
    int bidx = 0x7fffffff;
#pragma unroll
    for (int g = 0; g < NCHUNK / 64; ++g) {
      const int c = g * 64 + lane;
      const float v = sMaxV[c];
      const int i = sMaxI[c];
      const bool take = (v > bv) || (v == bv && i < bidx);
      bv = take ? v : bv;
      bidx = take ? i : bidx;
    }
    const float V = __int_as_float(
        __builtin_amdgcn_readlane(__float_as_int(vmax_wave(bv)), 63));
    const int fi = win_index(bv, V, __int_as_float(bidx));
    if (t == 0) idx_out[b * SS + it] = fi;
    // uniform (scalar) loads of winner coords
    lx = p[fi * 3 + 0];
    ly = p[fi * 3 + 1];
    lz = p[fi * 3 + 2];
  }
}

// ---------------- Ball query: one wave per centroid ----------------
__global__ __launch_bounds__(256) void ballq_kernel(const float* __restrict__ pos,
                                                    const int* __restrict__ idx,
                                                    int* __restrict__ nbr,
                                                    int* __restrict__ cnt,
                                                    float* __restrict__ outC,
                                                    float* __restrict__ outB) {
  const int cs = blockIdx.x * 4 + (threadIdx.x >> 6);
  const int lane = threadIdx.x & 63;
  const int b = cs >> 12;           // S = 4096
  const int s = cs & (SS - 1);
  const float* __restrict__ p = pos + (size_t)b * NN * 3;
  const int ci = idx[cs];
  const float cx = p[ci * 3 + 0], cy = p[ci * 3 + 1], cz = p[ci * 3 + 2];
  // remove_self_loops: global src b*N+i == global dst b*S+s -> only b==0, i==s
  const int excl = (b == 0) ? s : -1;
  int count = 0;
  for (int tile = 0; tile < NN / 64; ++tile) {
    const int i = tile * 64 + lane;
    const float dx = cx - p[i * 3 + 0];
    const float dy = cy - p[i * 3 + 1];
    const float dz = cz - p[i * 3 + 2];
    const float d2 = __fadd_rn(__fadd_rn(__fmul_rn(dx, dx), __fmul_rn(dy, dy)), __fmul_rn(dz, dz));
    const bool in = (d2 <= R2C) && (i != excl);
    const unsigned long long m = __ballot(in);
    if (in) {
      const int rank = count + (int)__popcll(m & ((1ull << lane) - 1ull));
      if (rank < KK) nbr[cs * KK + rank] = i;
    }
    count += (int)__popcll(m);
    if (count >= KK) break;
  }
  if (lane == 0) {
    cnt[cs] = count < KK ? count : KK;
    outC[cs * 3 + 0] = cx;
    outC[cs * 3 + 1] = cy;
    outC[cs * 3 + 2] = cz;
    outB[cs] = (float)b;
  }
}

// ---------------- MLP + max: one block (128 thr) per centroid ----------------
#define EE 33
__global__ __launch_bounds__(128) void mlp_kernel(const float* __restrict__ x,
                                                  const float* __restrict__ pos,
                                                  const int* __restrict__ nbr,
                                                  const int* __restrict__ cnt,
                                                  const float* __restrict__ W1,
                                                  const float* __restrict__ b1,
                                                  const float* __restrict__ W2,
                                                  const float* __restrict__ b2,
                                                  const float* __restrict__ W3,
                                                  const float* __restrict__ b3,
                                                  const float* __restrict__ outC,
                                                  float* __restrict__ outX) {
  __shared__ float sF[EE][20];
  __shared__ float sH1[EE][64];
  __shared__ float sH2[EE][64];
  __shared__ int sValid[EE];

  const int cs = blockIdx.x;
  const int tid = threadIdx.x;
  const int b = cs >> 12;
  const int c = tid & 63;
  const int half = tid >> 6;

  float w1c[19], w2c[64], w3c[64];
#pragma unroll
  for (int k = 0; k < 19; ++k) w1c[k] = W1[k * 64 + c];
#pragma unroll
  for (int k = 0; k < 64; ++k) w2c[k] = W2[k * 64 + c];
#pragma unroll
  for (int k = 0; k < 64; ++k) w3c[k] = W3[k * 128 + tid];
  const float b1c = b1[c], b2c = b2[c], b3c = b3[tid];

  if (tid < EE) {
    const float ccx = outC[cs * 3 + 0], ccy = outC[cs * 3 + 1], ccz = outC[cs * 3 + 2];
    int row;
    bool valid;
    if (tid < KK) {
      const int cn = cnt[cs];
      valid = tid < cn;
      const int j = valid ? nbr[cs * KK + tid] : 0;
      row = b * NN + j;
    } else {
      // PyG add_self_loops quirk: src is flat point index dflat = b*S+s = cs
      valid = true;
      row = cs;
    }
    for (int f = 0; f < FIN; ++f) sF[tid][f] = x[(size_t)row * FIN + f];
    sF[tid][16] = pos[(size_t)row * 3 + 0] - ccx;
    sF[tid][17] = pos[(size_t)row * 3 + 1] - ccy;
    sF[tid][18] = pos[(size_t)row * 3 + 2] - ccz;
    sValid[tid] = valid ? 1 : 0;
  }
  __syncthreads();
  for (int e = half; e < EE; e += 2) {
    float acc = b1c;
#pragma unroll
    for (int k = 0; k < 19; ++k) acc += sF[e][k] * w1c[k];
    sH1[e][c] = fmaxf(acc, 0.0f);
  }
  __syncthreads();
  for (int e = half; e < EE; e += 2) {
    float acc = b2c;
#pragma unroll
    for (int k = 0; k < 64; ++k) acc += sH1[e][k] * w2c[k];
    sH2[e][c] = fmaxf(acc, 0.0f);
  }
  __syncthreads();
  float mx = -1e30f;
  for (int e = 0; e < EE; ++e) {
    if (sValid[e]) {
      float acc = b3c;
#pragma unroll
      for (int k = 0; k < 64; ++k) acc += sH2[e][k] * w3c[k];
      mx = fmaxf(mx, acc);
    }
  }
  outX[(size_t)cs * 128 + tid] = mx;
}

extern "C" void kernel_launch(void* const* d_in, const int* in_sizes, int n_in,
                              void* d_out, int out_size, void* d_ws, size_t ws_size,
                              hipStream_t stream) {
  const float* x = (const float*)d_in[0];
  const float* pos = (const float*)d_in[1];
  const float* W1 = (const float*)d_in[3];
  const float* b1 = (const float*)d_in[4];
  const float* W2 = (const float*)d_in[5];
  const float* b2 = (const float*)d_in[6];
  const float* W3 = (const float*)d_in[7];
  const float* b3 = (const float*)d_in[8];

  float* out = (float*)d_out;
  float* outX = out;                               // [B*S,128]
  float* outC = out + (size_t)BB * SS * 128;       // [B*S,3]
  float* outB = outC + (size_t)BB * SS * 3;        // [B*S]

  float4* cellpts = (float4*)d_ws;                         // BB*NN float4
  float4* bboxLo = cellpts + (size_t)BB * NN;              // BB*256
  float4* bboxHi = bboxLo + BB * NCHUNK;                   // BB*256
  int* idx = (int*)(bboxHi + BB * NCHUNK);                 // BB*SS
  int* nbr = idx + BB * SS;                                // BB*SS*KK
  int* cnt = nbr + (size_t)BB * SS * KK;                   // BB*SS

  hipLaunchKernelGGL(bin_kernel, dim3(BB), dim3(512), 0, stream, pos, cellpts, bboxLo, bboxHi);
  hipLaunchKernelGGL(fps_kernel, dim3(BB), dim3(512), 0, stream, pos, cellpts, bboxLo, bboxHi, idx);
  hipLaunchKernelGGL(ballq_kernel, dim3(BB * SS / 4), dim3(256), 0, stream,
                     pos, idx, nbr, cnt, outC, outB);
  hipLaunchKernelGGL(mlp_kernel, dim3(BB * SS), dim3(128), 0, stream,
                     x, pos, nbr, cnt, W1, b1, W2, b2, W3, b3, outC, outX);
}